// Round 7
// baseline (965.097 us; speedup 1.0000x reference)
//
#include <hip/hip_runtime.h>

namespace {

constexpr float ALPHA = 0.2f;
constexpr float TAU   = 0.25f;
constexpr int   NITER = 10;

constexpr int H = 256, W = 256;
constexpr int TILE = 64;
constexpr int HALO = 10;             // = NITER dependency radius (Chebyshev)
constexpr int RG   = TILE + 2*HALO;  // 84 region rows/cols
constexpr int QR   = RG / 4;         // 21 quads per region row
constexpr int RQ   = RG / 4;         // 21 four-row groups
constexpr int NTH  = RQ * QR;        // 441 active threads
constexpr int NT   = 448;            // 7 waves; target 3 blocks/CU = 21 waves

// LDS (inter-thread exchange only), all accesses b128:
//   su_r0 [22][84]    : u rows ==0 mod 4, row-major   (down-neighbor: read +RG)
//   su_c0 [23][21][4] : u elem0-of-quad, transposed   (right-neighbor: read +RG)
//   spy   [21][84]    : py rows ==3 mod 4, row-major  (up-neighbor: read -RG)
//   spx   [23][21][4] : px elem3-of-quad, transposed  (left-neighbor: read -RG)
//   dump  [128]       : pad lanes' unconditional accesses land here
// Stray halo reads stay inside this block, are bounded, corrupt only region
// edge cells; edge garbage propagates 1 cell/iter -> reaches rows/cols <=9 or
// >=74, never the 10..73 output window.
constexpr int SUR0_OFF = 0;
constexpr int SUC0_OFF = SUR0_OFF + 22 * RG;   // 1848
constexpr int SPY_OFF  = SUC0_OFF + 23 * RG;   // 3780
constexpr int SPX_OFF  = SPY_OFF  + 21 * RG;   // 5544
constexpr int DUMP_OFF = SPX_OFF  + 23 * RG;   // 7476
constexpr int LDS_FLOATS = DUMP_OFF + 128;     // 7604 floats = 30416 B

// Pad-lane overrides (relative to each array base; all accesses land in dump):
constexpr int D_SUR0 = DUMP_OFF - SUR0_OFF;        // W @0,  R @+84
constexpr int D_SUC0 = DUMP_OFF - SUC0_OFF;        // W @0,  R @+84
constexpr int D_SPY  = DUMP_OFF - SPY_OFF + 84;    // W @84, R @0
constexpr int D_SPX  = DUMP_OFF - SPX_OFF + 84;    // W @84, R @0

typedef float v2f __attribute__((ext_vector_type(2)));

#if defined(__has_builtin)
#if __has_builtin(__builtin_amdgcn_rsqf)
#define RSQ(x) __builtin_amdgcn_rsqf(x)
#endif
#endif
#ifndef RSQ
#define RSQ(x) rsqrtf(x)
#endif

__launch_bounds__(NT, 6)   // unified-reg cap 85 -> 24-wave allowance -> 3 blocks
__global__ void tv_lrelu_kernel(const float* __restrict__ z,
                                const float* __restrict__ lam_p,
                                float* __restrict__ out) {
  __shared__ __align__(16) float lds[LDS_FLOATS];
  float* const su_r0 = lds + SUR0_OFF;
  float* const su_c0 = lds + SUC0_OFF;
  float* const spy   = lds + SPY_OFF;
  float* const spx   = lds + SPX_OFF;

  const float lam_c = fminf(fmaxf(lam_p[0], 0.0f), 1.0f);  // uniform -> SGPR
  const float cg    = lam_c * TAU;
  const float nlam  = -lam_c;

  const int b   = blockIdx.x;
  const int img = b >> 4;
  const int tr  = (b >> 2) & 3;
  const int tc  = b & 3;
  const int r0 = tr * TILE - HALO;
  const int c0 = tc * TILE - HALO;

  const int tid = threadIdx.x;
  const bool act = tid < NTH;
  const int tw = act ? tid : 0;       // pad lanes alias task 0 (reads only)
  const int rq = tw / QR;             // 4-row group index
  const int qc = tw - rq * QR;        // quad column
  const int r  = 4 * rq;              // top region row of this thread
  const int gi0 = r0 + r;
  const int gj  = c0 + qc * 4;

  // Column boundary masks (lane-varying, kept in regs).
  v2f cgx[2], nlmdx[2];
#pragma unroll
  for (int k = 0; k < 4; ++k) {
    reinterpret_cast<float*>(cgx)[k]   = (gj + k < W - 1) ? cg : 0.0f;
    reinterpret_cast<float*>(nlmdx)[k] = (gj + k > 0) ? nlam : 0.0f;
  }

  // z is NOT kept in registers: re-read from L2 every iteration (region is
  // L2-resident). Per row, two independently column-clamped float2 loads so
  // image-edge straddling quads keep their in-image elements exact; fully
  // out-of-image elements read bounded garbage (don't-care: boundary masks
  // cut every cross-image-edge dependency).
  const float* zb = z + (size_t)img * (H * W);   // uniform -> SGPR base
  const int ajlo = min(max(gj, 0), W - 2);
  const int ajhi = min(max(gj + 2, 0), W - 2);
  int olo[4], ohi[4];
#pragma unroll
  for (int i = 0; i < 4; ++i) {
    const int gic = min(max(gi0 + i, 0), H - 1);
    olo[i] = gic * W + ajlo;
    ohi[i] = gic * W + ajhi;
  }

  // Per-thread loop state: u, px, py (4 rows x 2 col-pairs each).
  v2f u[4][2];
  v2f px[4][2] = {};
  v2f py[4][2] = {};

#pragma unroll
  for (int i = 0; i < 4; ++i) {
    const v2f zl = *reinterpret_cast<const v2f*>(zb + olo[i]);
    const v2f zh = *reinterpret_cast<const v2f*>(zb + ohi[i]);
    u[i][0] = __builtin_elementwise_max(zl, zl * ALPHA);
    u[i][1] = __builtin_elementwise_max(zh, zh * ALPHA);
  }

  // LDS offsets (loop-invariant); pad lanes redirected into the dump zone so
  // every loop-body LDS op is unconditional (no exec-mask toggling).
  const int sw = act ? (rq * RG + qc * 4)       : D_SUR0;  // su_r0 W; R at +RG
  const int cw = act ? ((qc + 1) * RG + rq * 4) : D_SUC0;  // su_c0 W; R at +RG
  const int yw = act ? (rq * RG + qc * 4)       : D_SPY;   // spy   W; R at -RG
  const int xw = act ? ((qc + 1) * RG + rq * 4) : D_SPX;   // spx   W; R at -RG

  *reinterpret_cast<float4*>(&su_r0[sw]) =
      make_float4(u[0][0].x, u[0][0].y, u[0][1].x, u[0][1].y);
  *reinterpret_cast<float4*>(&su_c0[cw]) =
      make_float4(u[0][0].x, u[1][0].x, u[2][0].x, u[3][0].x);
  __syncthreads();

  for (int t = 0; t < NITER; ++t) {
    // Issue next-phase z loads early: latency hides under phase 1 + barrier.
    v2f zl[4], zh[4];
#pragma unroll
    for (int i = 0; i < 4; ++i) {
      zl[i] = *reinterpret_cast<const v2f*>(zb + olo[i]);
      zh[i] = *reinterpret_cast<const v2f*>(zb + ohi[i]);
    }

    // ---- phase 1: p += cg*grad(u), project onto unit ball ----
    const float4 udn = *reinterpret_cast<const float4*>(&su_r0[sw + RG]);
    const float4 ur4 = *reinterpret_cast<const float4*>(&su_c0[cw + RG]);
    const float ur[4] = {ur4.x, ur4.y, ur4.z, ur4.w};
    const v2f dn0 = {udn.x, udn.y}, dn1 = {udn.z, udn.w};

#pragma unroll
    for (int i = 0; i < 4; ++i) {
      const v2f un0 = {u[i][0].y, u[i][1].x};            // u(i, j+1)
      const v2f un1 = {u[i][1].y, ur[i]};
      const v2f ud0 = (i < 3) ? u[(i < 3) ? i + 1 : 0][0] : dn0;  // u(i+1, j)
      const v2f ud1 = (i < 3) ? u[(i < 3) ? i + 1 : 0][1] : dn1;
      const float cgy_i = (gi0 + i < H - 1) ? cg : 0.0f;  // recomputed, no reg

      px[i][0] = __builtin_elementwise_fma(cgx[0], un0 - u[i][0], px[i][0]);
      px[i][1] = __builtin_elementwise_fma(cgx[1], un1 - u[i][1], px[i][1]);
      py[i][0] = __builtin_elementwise_fma((v2f)cgy_i, ud0 - u[i][0], py[i][0]);
      py[i][1] = __builtin_elementwise_fma((v2f)cgy_i, ud1 - u[i][1], py[i][1]);
#pragma unroll
      for (int j = 0; j < 2; ++j) {
        // 1/max(norm,1) == rsqrt(max(norm^2,1)); rsq(1.0)=1.0 exactly.
        const v2f n2 = __builtin_elementwise_fma(px[i][j], px[i][j],
                                                 py[i][j] * py[i][j]);
        const v2f m = __builtin_elementwise_max(n2, (v2f)1.0f);
        const v2f sc = {RSQ(m.x), RSQ(m.y)};
        px[i][j] *= sc;
        py[i][j] *= sc;
      }
    }
    *reinterpret_cast<float4*>(&spx[xw]) =
        make_float4(px[0][1].y, px[1][1].y, px[2][1].y, px[3][1].y);
    *reinterpret_cast<float4*>(&spy[yw]) =
        make_float4(py[3][0].x, py[3][0].y, py[3][1].x, py[3][1].y);
    __syncthreads();

    // ---- phase 2: u = lrelu(z + lam*div(p)) ----
    const float4 pyu4 = *reinterpret_cast<const float4*>(&spy[yw - RG]);
    const float4 pxl4 = *reinterpret_cast<const float4*>(&spx[xw - RG]);
    const float pxl[4] = {pxl4.x, pxl4.y, pxl4.z, pxl4.w};
    const v2f up0 = {pyu4.x, pyu4.y}, up1 = {pyu4.z, pyu4.w};

#pragma unroll
    for (int i = 0; i < 4; ++i) {
      const v2f pxs0 = {pxl[i], px[i][0].x};             // px(i, j-1)
      const v2f pxs1 = {px[i][0].y, px[i][1].x};
      const v2f pyu0 = (i == 0) ? up0 : py[(i > 0) ? i - 1 : 0][0];
      const v2f pyu1 = (i == 0) ? up1 : py[(i > 0) ? i - 1 : 0][1];
      const float nlmy_i = (gi0 + i > 0) ? nlam : 0.0f;   // recomputed, no reg

      // a = z + lam*(px+py) - (lam*mdx)*pxl - (lam*mdy)*pyu
      v2f a0 = __builtin_elementwise_fma((v2f)lam_c, px[i][0] + py[i][0], zl[i]);
      v2f a1 = __builtin_elementwise_fma((v2f)lam_c, px[i][1] + py[i][1], zh[i]);
      a0 = __builtin_elementwise_fma(nlmdx[0], pxs0, a0);
      a1 = __builtin_elementwise_fma(nlmdx[1], pxs1, a1);
      a0 = __builtin_elementwise_fma((v2f)nlmy_i, pyu0, a0);
      a1 = __builtin_elementwise_fma((v2f)nlmy_i, pyu1, a1);
      u[i][0] = __builtin_elementwise_max(a0, a0 * ALPHA);
      u[i][1] = __builtin_elementwise_max(a1, a1 * ALPHA);
    }
    *reinterpret_cast<float4*>(&su_r0[sw]) =
        make_float4(u[0][0].x, u[0][0].y, u[0][1].x, u[0][1].y);
    *reinterpret_cast<float4*>(&su_c0[cw]) =
        make_float4(u[0][0].x, u[1][0].x, u[2][0].x, u[3][0].x);
    __syncthreads();
  }

  // ---- write center 64x64 tile straight from registers ----
  if (act) {
    const size_t base = (size_t)img * (H * W);
#pragma unroll
    for (int i = 0; i < 4; ++i) {
      const int rr = r + i;                       // region row
      if (rr >= HALO && rr < HALO + TILE) {
        float* dst = out + base + (long)(r0 + rr) * W + gj;
        if (qc >= 3 && qc <= 17) {                // quad fully inside cols 10..73
          *reinterpret_cast<float4*>(dst) =
              make_float4(u[i][0].x, u[i][0].y, u[i][1].x, u[i][1].y);
        } else if (qc == 2 || qc == 18) {         // partial edge quads
          const float uv[4] = {u[i][0].x, u[i][0].y, u[i][1].x, u[i][1].y};
#pragma unroll
          for (int k = 0; k < 4; ++k) {
            const int cc = qc * 4 + k;            // region col
            if (cc >= HALO && cc < HALO + TILE) dst[k] = uv[k];
          }
        }
      }
    }
  }
}

} // namespace

extern "C" void kernel_launch(void* const* d_in, const int* in_sizes, int n_in,
                              void* d_out, int out_size, void* d_ws, size_t ws_size,
                              hipStream_t stream) {
  const float* z   = (const float*)d_in[0];
  const float* lam = (const float*)d_in[1];
  float* out = (float*)d_out;

  const int n_img = in_sizes[0] / (H * W);    // 512 for (8,64,256,256)
  const int n_blocks = n_img * 16;            // 4x4 tiles per image

  tv_lrelu_kernel<<<n_blocks, NT, 0, stream>>>(z, lam, out);
}

// Round 8
// 377.007 us; speedup vs baseline: 2.5599x; 2.5599x over previous
//
#include <hip/hip_runtime.h>

namespace {

constexpr float ALPHA = 0.2f;
constexpr float TAU   = 0.25f;
constexpr int   NITER = 10;

constexpr int H = 256, W = 256;
constexpr int TILE = 64;
constexpr int HALO = 10;             // = NITER dependency radius (Chebyshev)
constexpr int RG   = TILE + 2*HALO;  // 84 region rows/cols
constexpr int QR   = RG / 4;         // 21 quad-columns per region row
constexpr int GW   = 21;             // lanes per row-group (3 groups + 1 pad per wave)
constexpr int NT   = 448;            // 7 waves = 21 row-groups; 441 active lanes

// LDS: double-buffered u-exchange rows only (ghost-p scheme removes p exchange;
// wave shuffles remove column exchange).
//   per buffer: sur0[21][84] (u row 0 of each group) | sur3[21][84] (u row 3)
//   reads: down = sur0[rq+1] (rq=20 overflows into sur3[0]: bounded garbage,
//          halo row); up = sur3[rq-1] (rq=0 underflows into sur0[20]: ditto).
//   dump[7*16]: pad lanes' unconditional accesses land here.
// Garbage containment (validated rounds 4-6): edge garbage propagates 1
// cell/iter, reaches rows/cols <=9 or >=74, never the 10..73 output window.
constexpr int SUR0 = 0;
constexpr int SUR3 = GW * RG;            // 1764
constexpr int BUF  = 2 * GW * RG;        // 3528 floats per buffer
constexpr int DUMP = 2 * BUF;            // 7056
constexpr int LDS_FLOATS = DUMP + 7 * 16;  // 7168 floats = 28672 B

typedef float v2f __attribute__((ext_vector_type(2)));

#if defined(__has_builtin)
#if __has_builtin(__builtin_amdgcn_rsqf)
#define RSQ(x) __builtin_amdgcn_rsqf(x)
#endif
#endif
#ifndef RSQ
#define RSQ(x) rsqrtf(x)
#endif

__launch_bounds__(NT, 4)   // unified cap 128: rounds 4-6 regime, no spills
__global__ void tv_lrelu_kernel(const float* __restrict__ z,
                                const float* __restrict__ lam_p,
                                float* __restrict__ out) {
  __shared__ __align__(16) float lds[LDS_FLOATS];

  const float lam_c = fminf(fmaxf(lam_p[0], 0.0f), 1.0f);
  const float cg    = lam_c * TAU;
  const float nlam  = -lam_c;

  const int b   = blockIdx.x;
  const int img = b >> 4;
  const int tr  = (b >> 2) & 3;
  const int tc  = b & 3;
  const long base = (long)img * (H * W);
  const int r0 = tr * TILE - HALO;
  const int c0 = tc * TILE - HALO;

  const int tid  = threadIdx.x;
  const int wave = tid >> 6;
  const int lane = tid & 63;
  const bool act = lane < 63;          // lane 63 of each wave is the pad lane
  const int lg = act ? lane / GW : 0;  // group within wave (0..2)
  const int qc = act ? lane - lg * GW : 0;  // quad column (0..20)
  const int rq = wave * 3 + lg;        // row-group (0..20)
  const int r  = 4 * rq;               // top region row of this thread
  const int gi0 = r0 + r;
  const int gj  = c0 + qc * 4;
  const int laneP1 = lane + 1, laneM1 = lane - 1;  // shfl masks; seam garbage
                                                   // lands in halo cols

  // Boundary masks folded into coefficients (computed once).
  v2f cgx[2], nlmdx[2];
#pragma unroll
  for (int k = 0; k < 4; ++k) {
    reinterpret_cast<float*>(cgx)[k]   = (gj + k < W - 1) ? cg : 0.0f;
    reinterpret_cast<float*>(nlmdx)[k] = (gj + k > 0) ? nlam : 0.0f;
  }
  float cgy[4], nlmy[4];
#pragma unroll
  for (int i = 0; i < 4; ++i) {
    cgy[i]  = (gi0 + i < H - 1) ? cg : 0.0f;
    nlmy[i] = (gi0 + i > 0) ? nlam : 0.0f;
  }
  const float cgyG = (gi0 - 1 < H - 1) ? cg : 0.0f;  // ghost row r-1

  // Per-thread state: z, u, p for 4 rows x 2 col-pairs; ghost p for row r-1.
  v2f zq[4][2], u[4][2];
  v2f px[4][2] = {};
  v2f py[4][2] = {};
  v2f gpx[2] = {}, gpy[2] = {};        // p(r-1, gj..gj+3), jointly projected

#pragma unroll
  for (int i = 0; i < 4; ++i) {
    const int gi = gi0 + i;
    const bool rin = (gi >= 0) & (gi < H);
    const float* zp = z + base + (long)gi * W + gj;
    float zv[4];
#pragma unroll
    for (int k = 0; k < 4; ++k) {
      const bool cin = (gj + k >= 0) & (gj + k < W);
      zv[k] = (rin & cin) ? zp[k] : 0.0f;
    }
    zq[i][0] = (v2f){zv[0], zv[1]};
    zq[i][1] = (v2f){zv[2], zv[3]};
#pragma unroll
    for (int j = 0; j < 2; ++j)
      u[i][j] = __builtin_elementwise_max(zq[i][j], zq[i][j] * ALPHA);
  }

  // LDS float indices (buf0 absolute); pad lanes -> private dump slots.
  const int wi0 = act ? (SUR0 + rq * RG + qc * 4) : (DUMP + wave * 16);
  const int wi3 = act ? (SUR3 + rq * RG + qc * 4) : (DUMP + wave * 16 + 4);
  const int rdn = act ? (SUR0 + (rq + 1) * RG + qc * 4) : (DUMP + wave * 16 + 8);
  const int rup = act ? (SUR3 + (rq - 1) * RG + qc * 4) : (DUMP + wave * 16 + 8);
  const int bofs = act ? BUF : 0;      // pad lanes stay in the dump for buf1

  *reinterpret_cast<float4*>(&lds[wi0]) =
      make_float4(u[0][0].x, u[0][0].y, u[0][1].x, u[0][1].y);
  *reinterpret_cast<float4*>(&lds[wi3]) =
      make_float4(u[3][0].x, u[3][0].y, u[3][1].x, u[3][1].y);
  __syncthreads();

  for (int t = 0; t < NITER; ++t) {
    const int rb = (t & 1) ? bofs : 0;   // read buffer (prev-iter u)
    const int wb = (t & 1) ? 0 : bofs;   // write buffer (new u)

    // ---- phase 1: p += cg*grad(u), project; ghost row maintained locally ----
    const float4 up4 = *reinterpret_cast<const float4*>(&lds[rup + rb]); // u(r-1)
    const float4 dn4 = *reinterpret_cast<const float4*>(&lds[rdn + rb]); // u(r+4)
    const float ucor = __shfl(up4.x, laneP1);           // u(r-1, gj+4)
    float ur[4];
#pragma unroll
    for (int i = 0; i < 4; ++i) ur[i] = __shfl(u[i][0].x, laneP1);  // u(i, gj+4)

    // ghost p(r-1,*): identical op sequence to the owner's -> bit-equal.
    {
      const v2f g0 = {up4.x, up4.y}, g1 = {up4.z, up4.w};
      const v2f ung0 = {up4.y, up4.z}, ung1 = {up4.w, ucor};
      gpx[0] = __builtin_elementwise_fma(cgx[0], ung0 - g0, gpx[0]);
      gpx[1] = __builtin_elementwise_fma(cgx[1], ung1 - g1, gpx[1]);
      gpy[0] = __builtin_elementwise_fma((v2f)cgyG, u[0][0] - g0, gpy[0]);
      gpy[1] = __builtin_elementwise_fma((v2f)cgyG, u[0][1] - g1, gpy[1]);
#pragma unroll
      for (int j = 0; j < 2; ++j) {
        const v2f n2 = __builtin_elementwise_fma(gpx[j], gpx[j], gpy[j] * gpy[j]);
        const v2f m  = __builtin_elementwise_max(n2, (v2f)1.0f);
        const v2f sc = {RSQ(m.x), RSQ(m.y)};
        gpx[j] *= sc;
        gpy[j] *= sc;
      }
    }

    const v2f dn0 = {dn4.x, dn4.y}, dn1 = {dn4.z, dn4.w};
#pragma unroll
    for (int i = 0; i < 4; ++i) {
      const v2f un0 = {u[i][0].y, u[i][1].x};            // u(i, j+1)
      const v2f un1 = {u[i][1].y, ur[i]};
      const v2f ud0 = (i < 3) ? u[(i < 3) ? i + 1 : 0][0] : dn0;  // u(i+1, j)
      const v2f ud1 = (i < 3) ? u[(i < 3) ? i + 1 : 0][1] : dn1;

      px[i][0] = __builtin_elementwise_fma(cgx[0], un0 - u[i][0], px[i][0]);
      px[i][1] = __builtin_elementwise_fma(cgx[1], un1 - u[i][1], px[i][1]);
      py[i][0] = __builtin_elementwise_fma((v2f)cgy[i], ud0 - u[i][0], py[i][0]);
      py[i][1] = __builtin_elementwise_fma((v2f)cgy[i], ud1 - u[i][1], py[i][1]);
#pragma unroll
      for (int j = 0; j < 2; ++j) {
        // 1/max(norm,1) == rsqrt(max(norm^2,1)); rsq(1.0)=1.0 exactly.
        const v2f n2 = __builtin_elementwise_fma(px[i][j], px[i][j],
                                                 py[i][j] * py[i][j]);
        const v2f m = __builtin_elementwise_max(n2, (v2f)1.0f);
        const v2f sc = {RSQ(m.x), RSQ(m.y)};
        px[i][j] *= sc;
        py[i][j] *= sc;
      }
    }

    // ---- phase 2 (NO barrier: px-left via shuffle, py-up via ghost) ----
    float pxl[4];
#pragma unroll
    for (int i = 0; i < 4; ++i) pxl[i] = __shfl(px[i][1].y, laneM1); // px(i,gj-1)

#pragma unroll
    for (int i = 0; i < 4; ++i) {
      const v2f pxs0 = {pxl[i], px[i][0].x};             // px(i, j-1)
      const v2f pxs1 = {px[i][0].y, px[i][1].x};
      const v2f pyu0 = (i == 0) ? gpy[0] : py[(i > 0) ? i - 1 : 0][0];
      const v2f pyu1 = (i == 0) ? gpy[1] : py[(i > 0) ? i - 1 : 0][1];

      // a = z + lam*(px+py) - (lam*mdx)*pxl - (lam*mdy)*pyu
      v2f a0 = __builtin_elementwise_fma((v2f)lam_c, px[i][0] + py[i][0], zq[i][0]);
      v2f a1 = __builtin_elementwise_fma((v2f)lam_c, px[i][1] + py[i][1], zq[i][1]);
      a0 = __builtin_elementwise_fma(nlmdx[0], pxs0, a0);
      a1 = __builtin_elementwise_fma(nlmdx[1], pxs1, a1);
      a0 = __builtin_elementwise_fma((v2f)nlmy[i], pyu0, a0);
      a1 = __builtin_elementwise_fma((v2f)nlmy[i], pyu1, a1);
      u[i][0] = __builtin_elementwise_max(a0, a0 * ALPHA);
      u[i][1] = __builtin_elementwise_max(a1, a1 * ALPHA);
    }

    *reinterpret_cast<float4*>(&lds[wi0 + wb]) =
        make_float4(u[0][0].x, u[0][0].y, u[0][1].x, u[0][1].y);
    *reinterpret_cast<float4*>(&lds[wi3 + wb]) =
        make_float4(u[3][0].x, u[3][0].y, u[3][1].x, u[3][1].y);
    __syncthreads();
  }

  // ---- write center 64x64 tile straight from registers ----
  if (act) {
#pragma unroll
    for (int i = 0; i < 4; ++i) {
      const int rr = r + i;                       // region row
      if (rr >= HALO && rr < HALO + TILE) {
        float* dst = out + base + (long)(r0 + rr) * W + gj;
        if (qc >= 3 && qc <= 17) {                // quad fully inside cols 10..73
          *reinterpret_cast<float4*>(dst) =
              make_float4(u[i][0].x, u[i][0].y, u[i][1].x, u[i][1].y);
        } else if (qc == 2 || qc == 18) {         // partial edge quads
          const float uv[4] = {u[i][0].x, u[i][0].y, u[i][1].x, u[i][1].y};
#pragma unroll
          for (int k = 0; k < 4; ++k) {
            const int cc = qc * 4 + k;            // region col
            if (cc >= HALO && cc < HALO + TILE) dst[k] = uv[k];
          }
        }
      }
    }
  }
}

} // namespace

extern "C" void kernel_launch(void* const* d_in, const int* in_sizes, int n_in,
                              void* d_out, int out_size, void* d_ws, size_t ws_size,
                              hipStream_t stream) {
  const float* z   = (const float*)d_in[0];
  const float* lam = (const float*)d_in[1];
  float* out = (float*)d_out;

  const int n_img = in_sizes[0] / (H * W);    // 512 for (8,64,256,256)
  const int n_blocks = n_img * 16;            // 4x4 tiles per image

  tv_lrelu_kernel<<<n_blocks, NT, 0, stream>>>(z, lam, out);
}

// Round 9
// 315.108 us; speedup vs baseline: 3.0628x; 1.1964x over previous
//
#include <hip/hip_runtime.h>

namespace {

constexpr float ALPHA = 0.2f;
constexpr float TAU   = 0.25f;
constexpr int   NITER = 10;

constexpr int H = 256, W = 256;
constexpr int TILE = 64;
constexpr int HALO = 10;             // = NITER dependency radius (Chebyshev)
constexpr int RG   = TILE + 2*HALO;  // 84 region rows/cols
constexpr int QR   = RG / 4;         // 21 quad-columns per region row
constexpr int NT   = 448;            // 7 waves; 2 blocks/CU (16-wave regime)

// Lane mapping (per wave): lane = lg*21 + qc, lg=0..2, qc=0..20; lane 63 pad.
// Wave w owns region rows 12w..12w+11 (row-groups rq = 3w+lg), all 84 cols.
// => ALL horizontal neighbors and intra-wave vertical neighbors exchange via
// register shuffles (lockstep-fresh, no LDS, no barriers). Only wave seams
// (every 12 rows) go through LDS:
//   usur[8][21][4]: u row 12w (written by lg0 end-of-iter; read by wave w-1's
//                   lg2 after the end barrier -> prev-iter value, correct)
//   pyb [8][21][4]: py row 12w+11 (written by lg2 after phase 1; read by wave
//                   w+1's lg0 after the mid barrier -> current-iter, correct)
// Orphan slots (usur[7], pyb[0]) zeroed once: garbage they inject lands in
// region rows <=9 / >=74 after 10 iters, never the 10..73 output window
// (same containment argument validated rounds 4-6).
constexpr int SLOT = QR * 4;                  // 84 floats per seam row
constexpr int USUR = 0;
constexpr int PYB  = 8 * SLOT;                // 672
constexpr int LDS_FLOATS = 16 * SLOT;         // 1344 floats = 5376 B

typedef float v2f __attribute__((ext_vector_type(2)));

#if defined(__has_builtin)
#if __has_builtin(__builtin_amdgcn_rsqf)
#define RSQ(x) __builtin_amdgcn_rsqf(x)
#endif
#endif
#ifndef RSQ
#define RSQ(x) rsqrtf(x)
#endif

__launch_bounds__(NT, 4)   // unified cap 128: rounds 4-6 no-spill regime
__global__ void tv_lrelu_kernel(const float* __restrict__ z,
                                const float* __restrict__ lam_p,
                                float* __restrict__ out) {
  __shared__ __align__(16) float lds[LDS_FLOATS];

  const float lam_c = fminf(fmaxf(lam_p[0], 0.0f), 1.0f);
  const float cg    = lam_c * TAU;
  const float nlam  = -lam_c;

  const int b   = blockIdx.x;
  const int img = b >> 4;
  const int tr  = (b >> 2) & 3;
  const int tc  = b & 3;
  const long base = (long)img * (H * W);
  const int r0 = tr * TILE - HALO;
  const int c0 = tc * TILE - HALO;

  const int tid  = threadIdx.x;
  const int wave = tid >> 6;
  const int lane = tid & 63;
  const bool act = lane < 63;               // lane 63 = pad
  const int lg = act ? lane / QR : 0;       // row-group within wave (0..2)
  const int qc = act ? lane - lg * QR : 0;  // quad column (0..20)
  const int rq = wave * 3 + lg;
  const int r  = 4 * rq;                    // top region row of this thread
  const int gi0 = r0 + r;
  const int gj  = c0 + qc * 4;
  const bool isg0 = (lg == 0), isg2 = (lg == 2);
  const int lP1 = lane + 1, lM1 = lane - 1;     // horizontal shuffles
  const int lP21 = lane + 21, lM21 = lane - 21; // vertical (cross-group)
  // Out-of-range shuffle sources wrap mod 64 -> garbage that lands only in
  // halo rows/cols (out-of-region neighbors), contained as documented above.

  // Boundary masks folded into coefficients (computed once, kept in regs).
  v2f cgx[2], nlmdx[2];
#pragma unroll
  for (int k = 0; k < 4; ++k) {
    reinterpret_cast<float*>(cgx)[k]   = (gj + k < W - 1) ? cg : 0.0f;
    reinterpret_cast<float*>(nlmdx)[k] = (gj + k > 0) ? nlam : 0.0f;
  }
  float cgy[4], nlmy[4];
#pragma unroll
  for (int i = 0; i < 4; ++i) {
    cgy[i]  = (gi0 + i < H - 1) ? cg : 0.0f;
    nlmy[i] = (gi0 + i > 0) ? nlam : 0.0f;
  }

  // Per-thread state: z, u, p for 4 rows x 2 col-pairs. (~96 live regs total)
  v2f zq[4][2], u[4][2];
  v2f px[4][2] = {};
  v2f py[4][2] = {};

#pragma unroll
  for (int i = 0; i < 4; ++i) {
    const int gi = gi0 + i;
    const bool rin = (gi >= 0) & (gi < H);
    const float* zp = z + base + (long)gi * W + gj;
    float zv[4];
#pragma unroll
    for (int k = 0; k < 4; ++k) {
      const bool cin = (gj + k >= 0) & (gj + k < W);
      zv[k] = (rin & cin) ? zp[k] : 0.0f;
    }
    zq[i][0] = (v2f){zv[0], zv[1]};
    zq[i][1] = (v2f){zv[2], zv[3]};
#pragma unroll
    for (int j = 0; j < 2; ++j)
      u[i][j] = __builtin_elementwise_max(zq[i][j], zq[i][j] * ALPHA);
  }

  // Seam LDS indices (floats).
  const int su_w = USUR + wave * SLOT + qc * 4;        // lg0 writes u row 12w
  const int su_r = USUR + (wave + 1) * SLOT + qc * 4;  // lg2 reads row 12w+12
  const int py_w = PYB + (wave + 1) * SLOT + qc * 4;   // lg2 writes row 12w+11
  const int py_r = PYB + wave * SLOT + qc * 4;         // lg0 reads row 12w-1

  if (tid < SLOT) {                       // zero orphan slots once
    lds[USUR + 7 * SLOT + tid] = 0.0f;
    lds[PYB + tid] = 0.0f;
  }
  if (act & isg0)
    *reinterpret_cast<float4*>(&lds[su_w]) =
        make_float4(u[0][0].x, u[0][0].y, u[0][1].x, u[0][1].y);
  __syncthreads();

  for (int t = 0; t < NITER; ++t) {
    // ---- phase 1: p += cg*grad(u), project onto unit ball ----
    // Seam read (prev-iter u, consumed only by lg2's row 3 -> off crit path).
    const float4 usd4 = *reinterpret_cast<const float4*>(&lds[su_r]);
    // Intra-wave vertical: u(r+4) = lane+21's current u row 0 (lockstep).
    const float udx0 = __shfl(u[0][0].x, lP21);
    const float udy0 = __shfl(u[0][0].y, lP21);
    const float udx1 = __shfl(u[0][1].x, lP21);
    const float udy1 = __shfl(u[0][1].y, lP21);
    const v2f dn0 = isg2 ? (v2f){usd4.x, usd4.y} : (v2f){udx0, udy0};
    const v2f dn1 = isg2 ? (v2f){usd4.z, usd4.w} : (v2f){udx1, udy1};
    // Horizontal: u(i, gj+4) = lane+1's u[i][0].x (qc=20 -> halo garbage, ok).
    float ur[4];
#pragma unroll
    for (int i = 0; i < 4; ++i) ur[i] = __shfl(u[i][0].x, lP1);

#pragma unroll
    for (int i = 0; i < 4; ++i) {
      const v2f un0 = {u[i][0].y, u[i][1].x};            // u(i, j+1)
      const v2f un1 = {u[i][1].y, ur[i]};
      const v2f ud0 = (i < 3) ? u[(i < 3) ? i + 1 : 0][0] : dn0;  // u(i+1, j)
      const v2f ud1 = (i < 3) ? u[(i < 3) ? i + 1 : 0][1] : dn1;

      px[i][0] = __builtin_elementwise_fma(cgx[0], un0 - u[i][0], px[i][0]);
      px[i][1] = __builtin_elementwise_fma(cgx[1], un1 - u[i][1], px[i][1]);
      py[i][0] = __builtin_elementwise_fma((v2f)cgy[i], ud0 - u[i][0], py[i][0]);
      py[i][1] = __builtin_elementwise_fma((v2f)cgy[i], ud1 - u[i][1], py[i][1]);
#pragma unroll
      for (int j = 0; j < 2; ++j) {
        // 1/max(norm,1) == rsqrt(max(norm^2,1)); rsq(1.0)=1.0 exactly.
        const v2f n2 = __builtin_elementwise_fma(px[i][j], px[i][j],
                                                 py[i][j] * py[i][j]);
        const v2f m = __builtin_elementwise_max(n2, (v2f)1.0f);
        const v2f sc = {RSQ(m.x), RSQ(m.y)};
        px[i][j] *= sc;
        py[i][j] *= sc;
      }
    }
    if (act & isg2)
      *reinterpret_cast<float4*>(&lds[py_w]) =
          make_float4(py[3][0].x, py[3][0].y, py[3][1].x, py[3][1].y);
    __syncthreads();

    // ---- phase 2: u = lrelu(z + lam*div(p)) ----
    // Seam read (current-iter py, consumed only by lg0's row 0 -> done last).
    const float4 pyu4 = *reinterpret_cast<const float4*>(&lds[py_r]);
    const float pux0 = __shfl(py[3][0].x, lM21);
    const float puy0 = __shfl(py[3][0].y, lM21);
    const float pux1 = __shfl(py[3][1].x, lM21);
    const float puy1 = __shfl(py[3][1].y, lM21);
    const v2f up0 = isg0 ? (v2f){pyu4.x, pyu4.y} : (v2f){pux0, puy0};
    const v2f up1 = isg0 ? (v2f){pyu4.z, pyu4.w} : (v2f){pux1, puy1};
    float pxl[4];
#pragma unroll
    for (int i = 0; i < 4; ++i) pxl[i] = __shfl(px[i][1].y, lM1); // px(i,gj-1)

#pragma unroll
    for (int ii = 0; ii < 4; ++ii) {
      const int i = 3 - ii;                 // rows 3..0: seam row (0) last
      const v2f pxs0 = {pxl[i], px[i][0].x};             // px(i, j-1)
      const v2f pxs1 = {px[i][0].y, px[i][1].x};
      const v2f pyu0 = (i == 0) ? up0 : py[(i > 0) ? i - 1 : 0][0];
      const v2f pyu1 = (i == 0) ? up1 : py[(i > 0) ? i - 1 : 0][1];

      // a = z + lam*(px+py) - (lam*mdx)*pxl - (lam*mdy)*pyu
      v2f a0 = __builtin_elementwise_fma((v2f)lam_c, px[i][0] + py[i][0], zq[i][0]);
      v2f a1 = __builtin_elementwise_fma((v2f)lam_c, px[i][1] + py[i][1], zq[i][1]);
      a0 = __builtin_elementwise_fma(nlmdx[0], pxs0, a0);
      a1 = __builtin_elementwise_fma(nlmdx[1], pxs1, a1);
      a0 = __builtin_elementwise_fma((v2f)nlmy[i], pyu0, a0);
      a1 = __builtin_elementwise_fma((v2f)nlmy[i], pyu1, a1);
      u[i][0] = __builtin_elementwise_max(a0, a0 * ALPHA);
      u[i][1] = __builtin_elementwise_max(a1, a1 * ALPHA);
    }
    if (act & isg0)
      *reinterpret_cast<float4*>(&lds[su_w]) =
          make_float4(u[0][0].x, u[0][0].y, u[0][1].x, u[0][1].y);
    __syncthreads();
  }

  // ---- write center 64x64 tile straight from registers ----
  if (act) {
#pragma unroll
    for (int i = 0; i < 4; ++i) {
      const int rr = r + i;                       // region row
      if (rr >= HALO && rr < HALO + TILE) {
        float* dst = out + base + (long)(r0 + rr) * W + gj;
        if (qc >= 3 && qc <= 17) {                // quad fully inside cols 10..73
          *reinterpret_cast<float4*>(dst) =
              make_float4(u[i][0].x, u[i][0].y, u[i][1].x, u[i][1].y);
        } else if (qc == 2 || qc == 18) {         // partial edge quads
          const float uv[4] = {u[i][0].x, u[i][0].y, u[i][1].x, u[i][1].y};
#pragma unroll
          for (int k = 0; k < 4; ++k) {
            const int cc = qc * 4 + k;            // region col
            if (cc >= HALO && cc < HALO + TILE) dst[k] = uv[k];
          }
        }
      }
    }
  }
}

} // namespace

extern "C" void kernel_launch(void* const* d_in, const int* in_sizes, int n_in,
                              void* d_out, int out_size, void* d_ws, size_t ws_size,
                              hipStream_t stream) {
  const float* z   = (const float*)d_in[0];
  const float* lam = (const float*)d_in[1];
  float* out = (float*)d_out;

  const int n_img = in_sizes[0] / (H * W);    // 512 for (8,64,256,256)
  const int n_blocks = n_img * 16;            // 4x4 tiles per image

  tv_lrelu_kernel<<<n_blocks, NT, 0, stream>>>(z, lam, out);
}

// Round 11
// 257.418 us; speedup vs baseline: 3.7491x; 1.2241x over previous
//
#include <hip/hip_runtime.h>

namespace {

constexpr float ALPHA = 0.2f;
constexpr float TAU   = 0.25f;
constexpr int   NITER = 10;

constexpr int H = 256, W = 256;
constexpr int TILE = 64;
constexpr int HALO = 10;             // = NITER dependency radius (Chebyshev)
constexpr int RG   = TILE + 2*HALO;  // 84 region rows/cols
constexpr int QR   = RG / 4;         // 21 quad-columns per region row
constexpr int RQ   = RG / 4;         // 21 four-row groups
constexpr int NTH  = RQ * QR;        // 441 active threads
constexpr int NT   = 448;            // 7 waves; target 4 blocks/CU = 28 waves

// fp16 port of the round-6 structure (best known: 289us). All state and loop
// math in _Float16 (v_pk_*_f16 = same issue rate as pk_f32, half the VGPRs)
// so true register usage fits the 64-reg cap -> 32-wave ceiling -> 4 blocks.
//
// LDS (f16 units), same exchange topology as round 6:
//   su_r0 [22][84] f16 : u rows ==0 mod 4       (down-neighbor: read +84)
//   su_c0 [23][21] h4  : u elem0-of-quad, transposed, +1 col shift (read +21)
//   spy   [21][84] f16 : py rows ==3 mod 4      (up-neighbor: read -84)
//   spx   [23][21] h4  : px elem3-of-quad, transposed, +1 col shift (read -21)
//   dump  [128]   f16  : pad lanes' unconditional accesses
// Stray/orphan reads (su_r0 row 21, su_c0 col 0/22, spx col 0, spy rq=0
// negative offset -> lands in su_c0 tail) stay inside this block; garbage
// (even NaN) corrupts only region edge cells and propagates 1 cell/iter ->
// reaches rows/cols <=9 or >=74, never the 10..73 output window (containment
// validated rounds 4-6 with identical topology).
constexpr int SUR0 = 0;                       // f16 idx
constexpr int SUC0 = 22 * RG;                 // 1848
constexpr int SPY  = SUC0 + 23 * QR * 4;      // 1848 + 1932 = 3780
constexpr int SPX  = SPY + 21 * RG;           // 5544
constexpr int DUMP = SPX + 23 * QR * 4;       // 7476
constexpr int LDS_F16 = DUMP + 128;           // 7604 f16 = 15208 B -> 4 blocks ok

typedef _Float16 h2 __attribute__((ext_vector_type(2)));
typedef _Float16 h4 __attribute__((ext_vector_type(4)));

#if defined(__has_builtin)
#if __has_builtin(__builtin_amdgcn_rsqh)
#define RSQH(x) static_cast<_Float16>(__builtin_amdgcn_rsqh(x))
#endif
#endif
#ifndef RSQH
#define RSQH(x) static_cast<_Float16>(__builtin_amdgcn_rsqf((float)(x)))
#endif

__launch_bounds__(NT, 8)   // VGPR cap 64: the whole point (f16 state ~60 live)
__global__ void tv_lrelu_kernel(const float* __restrict__ z,
                                const float* __restrict__ lam_p,
                                float* __restrict__ out) {
  __shared__ __align__(16) _Float16 lds[LDS_F16];
  _Float16* const su_r0 = lds + SUR0;
  h4* const       su_c0 = reinterpret_cast<h4*>(lds + SUC0);
  _Float16* const spy   = lds + SPY;
  h4* const       spx   = reinterpret_cast<h4*>(lds + SPX);

  const float lam_f = fminf(fmaxf(lam_p[0], 0.0f), 1.0f);
  const _Float16 lam_c = (_Float16)lam_f;
  const _Float16 cg    = (_Float16)(lam_f * TAU);
  const _Float16 nlam  = (_Float16)(-lam_f);
  const _Float16 alh   = (_Float16)ALPHA;

  const int b   = blockIdx.x;
  const int img = b >> 4;
  const int tr  = (b >> 2) & 3;
  const int tc  = b & 3;
  const long base = (long)img * (H * W);
  const int r0 = tr * TILE - HALO;
  const int c0 = tc * TILE - HALO;

  const int tid = threadIdx.x;
  const bool act = tid < NTH;
  const int tw = act ? tid : 0;       // pad lanes alias task 0 (reads only)
  const int rq = tw / QR;             // 4-row group index
  const int qc = tw - rq * QR;        // quad column
  const int r  = 4 * rq;              // top region row of this thread
  const int gi0 = r0 + r;
  const int gj  = c0 + qc * 4;

  // Boundary masks folded into f16 coefficients (computed once).
  h2 cgx[2], nlmdx[2];
#pragma unroll
  for (int k = 0; k < 4; ++k) {
    reinterpret_cast<_Float16*>(cgx)[k]   = (gj + k < W - 1) ? cg : (_Float16)0;
    reinterpret_cast<_Float16*>(nlmdx)[k] = (gj + k > 0) ? nlam : (_Float16)0;
  }
  _Float16 cgy[4], nlmy[4];
#pragma unroll
  for (int i = 0; i < 4; ++i) {
    cgy[i]  = (gi0 + i < H - 1) ? cg : (_Float16)0;
    nlmy[i] = (gi0 + i > 0) ? nlam : (_Float16)0;
  }

  // Per-thread state: z, u, p for 4 rows x 2 col-pairs, all f16 (~40 regs).
  h2 zq[4][2], u[4][2];
  h2 px[4][2] = {};
  h2 py[4][2] = {};

#pragma unroll
  for (int i = 0; i < 4; ++i) {
    const int gi = gi0 + i;
    const bool rin = (gi >= 0) & (gi < H);
    const float* zp = z + base + (long)gi * W + gj;
    float zv[4];
#pragma unroll
    for (int k = 0; k < 4; ++k) {
      const bool cin = (gj + k >= 0) & (gj + k < W);
      zv[k] = (rin & cin) ? zp[k] : 0.0f;
    }
    zq[i][0] = (h2){(_Float16)zv[0], (_Float16)zv[1]};
    zq[i][1] = (h2){(_Float16)zv[2], (_Float16)zv[3]};
#pragma unroll
    for (int j = 0; j < 2; ++j)
      u[i][j] = __builtin_elementwise_max(zq[i][j], zq[i][j] * alh);
  }

  // LDS indices (su_r0/spy in f16 units; su_c0/spx in h4 units).
  // Pad lanes -> dump zone so all loop LDS ops are unconditional.
  const int sw = act ? (rq * RG + qc * 4)  : DUMP;        // su_r0 W; R at +84
  const int cw = act ? ((qc + 1) * QR + rq) : (DUMP / 4); // su_c0 W; R at +21
  const int yw = act ? (rq * RG + qc * 4)  : (DUMP + 84); // spy   W; R at -84
  const int xw = act ? ((qc + 1) * QR + rq) : (DUMP / 4 + 21); // spx W; R at -21

  *reinterpret_cast<h4*>(&su_r0[sw]) =
      (h4){u[0][0].x, u[0][0].y, u[0][1].x, u[0][1].y};
  su_c0[cw] = (h4){u[0][0].x, u[1][0].x, u[2][0].x, u[3][0].x};
  __syncthreads();

  for (int t = 0; t < NITER; ++t) {
    // ---- phase 1: p += cg*grad(u), project onto unit ball ----
    const h4 usd = *reinterpret_cast<const h4*>(&su_r0[sw + RG]); // u(r+4)
    const h4 urq = su_c0[cw + QR];                                // u(i, gj+4)
    const _Float16 ur[4] = {urq.x, urq.y, urq.z, urq.w};
    const h2 dn0 = {usd.x, usd.y}, dn1 = {usd.z, usd.w};

#pragma unroll
    for (int i = 0; i < 4; ++i) {
      const h2 un0 = {u[i][0].y, u[i][1].x};             // u(i, j+1)
      const h2 un1 = {u[i][1].y, ur[i]};
      const h2 ud0 = (i < 3) ? u[(i < 3) ? i + 1 : 0][0] : dn0;  // u(i+1, j)
      const h2 ud1 = (i < 3) ? u[(i < 3) ? i + 1 : 0][1] : dn1;
      const h2 cgyv = {cgy[i], cgy[i]};

      px[i][0] = __builtin_elementwise_fma(cgx[0], un0 - u[i][0], px[i][0]);
      px[i][1] = __builtin_elementwise_fma(cgx[1], un1 - u[i][1], px[i][1]);
      py[i][0] = __builtin_elementwise_fma(cgyv,   ud0 - u[i][0], py[i][0]);
      py[i][1] = __builtin_elementwise_fma(cgyv,   ud1 - u[i][1], py[i][1]);
#pragma unroll
      for (int j = 0; j < 2; ++j) {
        // 1/max(norm,1) == rsqrt(max(norm^2,1)); rsq(1.0)=1.0 exactly.
        const h2 n2 = __builtin_elementwise_fma(px[i][j], px[i][j],
                                                py[i][j] * py[i][j]);
        const h2 m = __builtin_elementwise_max(n2, (h2){(_Float16)1, (_Float16)1});
        const h2 sc = {RSQH(m.x), RSQH(m.y)};
        px[i][j] *= sc;
        py[i][j] *= sc;
      }
    }
    spx[xw] = (h4){px[0][1].y, px[1][1].y, px[2][1].y, px[3][1].y};
    *reinterpret_cast<h4*>(&spy[yw]) =
        (h4){py[3][0].x, py[3][0].y, py[3][1].x, py[3][1].y};
    __syncthreads();

    // ---- phase 2: u = lrelu(z + lam*div(p)) ----
    const h4 pyu = *reinterpret_cast<const h4*>(&spy[yw - RG]);  // py(r-1)
    const h4 pxq = spx[xw - QR];                                 // px(i, gj-1)
    const _Float16 pxl[4] = {pxq.x, pxq.y, pxq.z, pxq.w};
    const h2 up0 = {pyu.x, pyu.y}, up1 = {pyu.z, pyu.w};
    const h2 lamv = {lam_c, lam_c};

#pragma unroll
    for (int i = 0; i < 4; ++i) {
      const h2 pxs0 = {pxl[i], px[i][0].x};              // px(i, j-1)
      const h2 pxs1 = {px[i][0].y, px[i][1].x};
      const h2 pyu0 = (i == 0) ? up0 : py[(i > 0) ? i - 1 : 0][0];
      const h2 pyu1 = (i == 0) ? up1 : py[(i > 0) ? i - 1 : 0][1];
      const h2 nlmyv = {nlmy[i], nlmy[i]};

      // a = z + lam*(px+py) - (lam*mdx)*pxl - (lam*mdy)*pyu
      h2 a0 = __builtin_elementwise_fma(lamv, px[i][0] + py[i][0], zq[i][0]);
      h2 a1 = __builtin_elementwise_fma(lamv, px[i][1] + py[i][1], zq[i][1]);
      a0 = __builtin_elementwise_fma(nlmdx[0], pxs0, a0);
      a1 = __builtin_elementwise_fma(nlmdx[1], pxs1, a1);
      a0 = __builtin_elementwise_fma(nlmyv, pyu0, a0);
      a1 = __builtin_elementwise_fma(nlmyv, pyu1, a1);
      u[i][0] = __builtin_elementwise_max(a0, a0 * alh);
      u[i][1] = __builtin_elementwise_max(a1, a1 * alh);
    }
    *reinterpret_cast<h4*>(&su_r0[sw]) =
        (h4){u[0][0].x, u[0][0].y, u[0][1].x, u[0][1].y};
    su_c0[cw] = (h4){u[0][0].x, u[1][0].x, u[2][0].x, u[3][0].x};
    __syncthreads();
  }

  // ---- write center 64x64 tile straight from registers (f16 -> f32) ----
  if (act) {
#pragma unroll
    for (int i = 0; i < 4; ++i) {
      const int rr = r + i;                       // region row
      if (rr >= HALO && rr < HALO + TILE) {
        float* dst = out + base + (long)(r0 + rr) * W + gj;
        const float uv[4] = {(float)u[i][0].x, (float)u[i][0].y,
                             (float)u[i][1].x, (float)u[i][1].y};
        if (qc >= 3 && qc <= 17) {                // quad fully inside cols 10..73
          *reinterpret_cast<float4*>(dst) =
              make_float4(uv[0], uv[1], uv[2], uv[3]);
        } else if (qc == 2 || qc == 18) {         // partial edge quads
#pragma unroll
          for (int k = 0; k < 4; ++k) {
            const int cc = qc * 4 + k;            // region col
            if (cc >= HALO && cc < HALO + TILE) dst[k] = uv[k];
          }
        }
      }
    }
  }
}

} // namespace

extern "C" void kernel_launch(void* const* d_in, const int* in_sizes, int n_in,
                              void* d_out, int out_size, void* d_ws, size_t ws_size,
                              hipStream_t stream) {
  const float* z   = (const float*)d_in[0];
  const float* lam = (const float*)d_in[1];
  float* out = (float*)d_out;

  const int n_img = in_sizes[0] / (H * W);    // 512 for (8,64,256,256)
  const int n_blocks = n_img * 16;            // 4x4 tiles per image

  tv_lrelu_kernel<<<n_blocks, NT, 0, stream>>>(z, lam, out);
}

// Round 12
// 255.613 us; speedup vs baseline: 3.7756x; 1.0071x over previous
//
#include <hip/hip_runtime.h>

namespace {

constexpr float ALPHA = 0.2f;
constexpr float TAU   = 0.25f;
constexpr int   NITER = 10;

constexpr int H = 256, W = 256;
constexpr int TILE = 64;
constexpr int HALO = 10;             // = NITER dependency radius (Chebyshev)
constexpr int RG   = TILE + 2*HALO;  // 84 region rows/cols
constexpr int QR   = RG / 4;         // 21 quad-columns per region row
constexpr int RQ   = RG / 4;         // 21 four-row groups
constexpr int NTH  = RQ * QR;        // 441 active threads
constexpr int NT   = 448;            // 7 waves; target 4 blocks/CU = 28 waves

// fp16 port of the round-6 structure. All state and loop math in _Float16
// (v_pk_*_f16 = same issue rate as pk_f32, half the VGPRs).
//
// LDS (f16 units), same exchange topology as round 6:
//   su_r0 [22][84] f16 : u rows ==0 mod 4       (down-neighbor: read +84)
//   su_c0 [23][21] h4  : u elem0-of-quad, transposed, +1 col shift (read +21)
//   spy   [21][84] f16 : py rows ==3 mod 4      (up-neighbor: read -84)
//   spx   [23][21] h4  : px elem3-of-quad, transposed, +1 col shift (read -21)
//   dump  [128]   f16  : pad lanes' unconditional accesses
// Stray/orphan reads stay inside this block; garbage (even NaN) corrupts only
// region edge cells and propagates 1 cell/iter -> reaches rows/cols <=9 or
// >=74, never the 10..73 output window (containment validated rounds 4-6).
constexpr int SUR0 = 0;                       // f16 idx
constexpr int SUC0 = 22 * RG;                 // 1848
constexpr int SPY  = SUC0 + 23 * QR * 4;      // 1848 + 1932 = 3780
constexpr int SPX  = SPY + 21 * RG;           // 5544
constexpr int DUMP = SPX + 23 * QR * 4;       // 7476
constexpr int LDS_F16 = DUMP + 128;           // 7604 f16 = 15208 B

typedef _Float16 h2 __attribute__((ext_vector_type(2)));
typedef _Float16 h4 __attribute__((ext_vector_type(4)));

#if defined(__has_builtin)
#if __has_builtin(__builtin_amdgcn_rsqh)
#define RSQH(x) static_cast<_Float16>(__builtin_amdgcn_rsqh(x))
#endif
#endif
#ifndef RSQH
#define RSQH(x) static_cast<_Float16>(__builtin_amdgcn_rsqf((float)(x)))
#endif

// min-waves 7 (NOT 8): 4 blocks/CU needs 28 waves -> 2048/28 = 73-reg cap.
// Round 11's (NT,8) forced a 64-reg cap; the allocator hit 36 VGPRs by
// serializing dependent chains -- ILP starvation. 9 more regs, same 4-block
// wave budget.
__launch_bounds__(NT, 7)
__global__ void tv_lrelu_kernel(const float* __restrict__ z,
                                const float* __restrict__ lam_p,
                                float* __restrict__ out) {
  __shared__ __align__(16) _Float16 lds[LDS_F16];
  _Float16* const su_r0 = lds + SUR0;
  h4* const       su_c0 = reinterpret_cast<h4*>(lds + SUC0);
  _Float16* const spy   = lds + SPY;
  h4* const       spx   = reinterpret_cast<h4*>(lds + SPX);

  const float lam_f = fminf(fmaxf(lam_p[0], 0.0f), 1.0f);
  const _Float16 lam_c = (_Float16)lam_f;
  const _Float16 cg    = (_Float16)(lam_f * TAU);
  const _Float16 nlam  = (_Float16)(-lam_f);
  const _Float16 alh   = (_Float16)ALPHA;

  const int b   = blockIdx.x;
  const int img = b >> 4;
  const int tr  = (b >> 2) & 3;
  const int tc  = b & 3;
  const long base = (long)img * (H * W);
  const int r0 = tr * TILE - HALO;
  const int c0 = tc * TILE - HALO;

  const int tid = threadIdx.x;
  const bool act = tid < NTH;
  const int tw = act ? tid : 0;       // pad lanes alias task 0 (reads only)
  const int rq = tw / QR;             // 4-row group index
  const int qc = tw - rq * QR;        // quad column
  const int r  = 4 * rq;              // top region row of this thread
  const int gi0 = r0 + r;
  const int gj  = c0 + qc * 4;

  // Boundary masks folded into f16 coefficients (computed once).
  h2 cgx[2], nlmdx[2];
#pragma unroll
  for (int k = 0; k < 4; ++k) {
    reinterpret_cast<_Float16*>(cgx)[k]   = (gj + k < W - 1) ? cg : (_Float16)0;
    reinterpret_cast<_Float16*>(nlmdx)[k] = (gj + k > 0) ? nlam : (_Float16)0;
  }
  _Float16 cgy[4], nlmy[4];
#pragma unroll
  for (int i = 0; i < 4; ++i) {
    cgy[i]  = (gi0 + i < H - 1) ? cg : (_Float16)0;
    nlmy[i] = (gi0 + i > 0) ? nlam : (_Float16)0;
  }

  // Per-thread state: z, u, p for 4 rows x 2 col-pairs, all f16.
  h2 zq[4][2], u[4][2];
  h2 px[4][2] = {};
  h2 py[4][2] = {};

#pragma unroll
  for (int i = 0; i < 4; ++i) {
    const int gi = gi0 + i;
    const bool rin = (gi >= 0) & (gi < H);
    const float* zp = z + base + (long)gi * W + gj;
    float zv[4];
#pragma unroll
    for (int k = 0; k < 4; ++k) {
      const bool cin = (gj + k >= 0) & (gj + k < W);
      zv[k] = (rin & cin) ? zp[k] : 0.0f;
    }
    zq[i][0] = (h2){(_Float16)zv[0], (_Float16)zv[1]};
    zq[i][1] = (h2){(_Float16)zv[2], (_Float16)zv[3]};
#pragma unroll
    for (int j = 0; j < 2; ++j)
      u[i][j] = __builtin_elementwise_max(zq[i][j], zq[i][j] * alh);
  }

  // LDS indices (su_r0/spy in f16 units; su_c0/spx in h4 units).
  // Pad lanes -> dump zone so all loop LDS ops are unconditional.
  const int sw = act ? (rq * RG + qc * 4)  : DUMP;        // su_r0 W; R at +84
  const int cw = act ? ((qc + 1) * QR + rq) : (DUMP / 4); // su_c0 W; R at +21
  const int yw = act ? (rq * RG + qc * 4)  : (DUMP + 84); // spy   W; R at -84
  const int xw = act ? ((qc + 1) * QR + rq) : (DUMP / 4 + 21); // spx W; R at -21

  *reinterpret_cast<h4*>(&su_r0[sw]) =
      (h4){u[0][0].x, u[0][0].y, u[0][1].x, u[0][1].y};
  su_c0[cw] = (h4){u[0][0].x, u[1][0].x, u[2][0].x, u[3][0].x};
  __syncthreads();

  for (int t = 0; t < NITER; ++t) {
    // ---- phase 1: p += cg*grad(u), project onto unit ball ----
    const h4 usd = *reinterpret_cast<const h4*>(&su_r0[sw + RG]); // u(r+4)
    const h4 urq = su_c0[cw + QR];                                // u(i, gj+4)
    const _Float16 ur[4] = {urq.x, urq.y, urq.z, urq.w};
    const h2 dn0 = {usd.x, usd.y}, dn1 = {usd.z, usd.w};

#pragma unroll
    for (int i = 0; i < 4; ++i) {
      const h2 un0 = {u[i][0].y, u[i][1].x};             // u(i, j+1)
      const h2 un1 = {u[i][1].y, ur[i]};
      const h2 ud0 = (i < 3) ? u[(i < 3) ? i + 1 : 0][0] : dn0;  // u(i+1, j)
      const h2 ud1 = (i < 3) ? u[(i < 3) ? i + 1 : 0][1] : dn1;
      const h2 cgyv = {cgy[i], cgy[i]};

      px[i][0] = __builtin_elementwise_fma(cgx[0], un0 - u[i][0], px[i][0]);
      px[i][1] = __builtin_elementwise_fma(cgx[1], un1 - u[i][1], px[i][1]);
      py[i][0] = __builtin_elementwise_fma(cgyv,   ud0 - u[i][0], py[i][0]);
      py[i][1] = __builtin_elementwise_fma(cgyv,   ud1 - u[i][1], py[i][1]);
#pragma unroll
      for (int j = 0; j < 2; ++j) {
        // 1/max(norm,1) == rsqrt(max(norm^2,1)); rsq(1.0)=1.0 exactly.
        const h2 n2 = __builtin_elementwise_fma(px[i][j], px[i][j],
                                                py[i][j] * py[i][j]);
        const h2 m = __builtin_elementwise_max(n2, (h2){(_Float16)1, (_Float16)1});
        const h2 sc = {RSQH(m.x), RSQH(m.y)};
        px[i][j] *= sc;
        py[i][j] *= sc;
      }
    }
    spx[xw] = (h4){px[0][1].y, px[1][1].y, px[2][1].y, px[3][1].y};
    *reinterpret_cast<h4*>(&spy[yw]) =
        (h4){py[3][0].x, py[3][0].y, py[3][1].x, py[3][1].y};
    __syncthreads();

    // ---- phase 2: u = lrelu(z + lam*div(p)) ----
    const h4 pyu = *reinterpret_cast<const h4*>(&spy[yw - RG]);  // py(r-1)
    const h4 pxq = spx[xw - QR];                                 // px(i, gj-1)
    const _Float16 pxl[4] = {pxq.x, pxq.y, pxq.z, pxq.w};
    const h2 up0 = {pyu.x, pyu.y}, up1 = {pyu.z, pyu.w};
    const h2 lamv = {lam_c, lam_c};

#pragma unroll
    for (int i = 0; i < 4; ++i) {
      const h2 pxs0 = {pxl[i], px[i][0].x};              // px(i, j-1)
      const h2 pxs1 = {px[i][0].y, px[i][1].x};
      const h2 pyu0 = (i == 0) ? up0 : py[(i > 0) ? i - 1 : 0][0];
      const h2 pyu1 = (i == 0) ? up1 : py[(i > 0) ? i - 1 : 0][1];
      const h2 nlmyv = {nlmy[i], nlmy[i]};

      // a = z + lam*(px+py) - (lam*mdx)*pxl - (lam*mdy)*pyu
      h2 a0 = __builtin_elementwise_fma(lamv, px[i][0] + py[i][0], zq[i][0]);
      h2 a1 = __builtin_elementwise_fma(lamv, px[i][1] + py[i][1], zq[i][1]);
      a0 = __builtin_elementwise_fma(nlmdx[0], pxs0, a0);
      a1 = __builtin_elementwise_fma(nlmdx[1], pxs1, a1);
      a0 = __builtin_elementwise_fma(nlmyv, pyu0, a0);
      a1 = __builtin_elementwise_fma(nlmyv, pyu1, a1);
      u[i][0] = __builtin_elementwise_max(a0, a0 * alh);
      u[i][1] = __builtin_elementwise_max(a1, a1 * alh);
    }
    // Last iteration: nobody reads su again -> skip dead writes + barrier.
    if (t < NITER - 1) {
      *reinterpret_cast<h4*>(&su_r0[sw]) =
          (h4){u[0][0].x, u[0][0].y, u[0][1].x, u[0][1].y};
      su_c0[cw] = (h4){u[0][0].x, u[1][0].x, u[2][0].x, u[3][0].x};
      __syncthreads();
    }
  }

  // ---- write center 64x64 tile straight from registers (f16 -> f32) ----
  if (act) {
#pragma unroll
    for (int i = 0; i < 4; ++i) {
      const int rr = r + i;                       // region row
      if (rr >= HALO && rr < HALO + TILE) {
        float* dst = out + base + (long)(r0 + rr) * W + gj;
        const float uv[4] = {(float)u[i][0].x, (float)u[i][0].y,
                             (float)u[i][1].x, (float)u[i][1].y};
        if (qc >= 3 && qc <= 17) {                // quad fully inside cols 10..73
          *reinterpret_cast<float4*>(dst) =
              make_float4(uv[0], uv[1], uv[2], uv[3]);
        } else if (qc == 2 || qc == 18) {         // partial edge quads
#pragma unroll
          for (int k = 0; k < 4; ++k) {
            const int cc = qc * 4 + k;            // region col
            if (cc >= HALO && cc < HALO + TILE) dst[k] = uv[k];
          }
        }
      }
    }
  }
}

} // namespace

extern "C" void kernel_launch(void* const* d_in, const int* in_sizes, int n_in,
                              void* d_out, int out_size, void* d_ws, size_t ws_size,
                              hipStream_t stream) {
  const float* z   = (const float*)d_in[0];
  const float* lam = (const float*)d_in[1];
  float* out = (float*)d_out;

  const int n_img = in_sizes[0] / (H * W);    // 512 for (8,64,256,256)
  const int n_blocks = n_img * 16;            // 4x4 tiles per image

  tv_lrelu_kernel<<<n_blocks, NT, 0, stream>>>(z, lam, out);
}